// Round 6
// baseline (100.031 us; speedup 1.0000x reference)
//
#include <hip/hip_runtime.h>
#include <stdint.h>

#define NB 8
#define NT 2048
#define NC 1024
#define HD 64

typedef __attribute__((ext_vector_type(8)))  short s16x8;
typedef __attribute__((ext_vector_type(4)))  float f32x4;
typedef __attribute__((ext_vector_type(16))) float f32x16;

__device__ inline ushort f2b(float f) {
    union { float f; uint32_t u; } c; c.f = f;
    uint32_t u = c.u;
    uint32_t r = (u + 0x7fffu + ((u >> 16) & 1u)) >> 16;   // RNE, finite inputs
    return (ushort)r;
}

__device__ inline uint32_t cvt_pk_bf16(float lo, float hi) {
    uint32_t r;
    asm("v_cvt_pk_bf16_f32 %0, %1, %2" : "=v"(r) : "v"(lo), "v"(hi));
    return r;
}

// ---------------------------------------------------------------------------
// Kernel 0: W [1024][192] f32  ->  Wt [192][1024] bf16, q-cols pre-scaled by
// 0.125 * log2(e) so attention logits are already base-2.
// ---------------------------------------------------------------------------
__global__ __launch_bounds__(256) void wprep(const float* __restrict__ W,
                                             ushort* __restrict__ wt) {
    int tid = blockIdx.x * 256 + threadIdx.x;   // 192*1024 total
    int n = tid >> 10;          // 0..191 (output col of qkv)
    int k = tid & 1023;         // 0..1023
    float v = W[k * 192 + n];
    if (n < 64) v *= 0.125f * 1.4426950408889634f;
    wt[n * 1024 + k] = f2b(v);
}

// ---------------------------------------------------------------------------
// Kernel 1: qkv = x @ W.  BM=64, grid 256 (1 block/CU), 8 waves, BK=64.
// T14 reg-staged pipeline: LINEAR global loads (clean coalescing, no source
// swizzle) -> registers (issue depth 3 = ~2 iterations of latency slack) ->
// padded LDS (A stride 272B, W stride 144B: all ds ops spread uniformly,
// 8 lanes per 16B bank-slot = b128 optimum). 3 LDS buffers, ONE barrier per
// K-step, sched_barrier(0) fences pin loads to their issue iteration.
// vmcnt fully compiler-managed (the wait lands at the ds_write site = T14).
// Wave (g,c): rows g*32..+32, cols c*48..+48; 12 MFMA 16x16x32 per K-step.
// ---------------------------------------------------------------------------
#define APITCH 272   // 64 f32 = 256 B + 16 B pad
#define WPITCH 144   // 64 bf16 = 128 B + 16 B pad

__global__ __launch_bounds__(512, 1) void qkv_gemm(const float* __restrict__ x,
                                                   const ushort* __restrict__ wt,
                                                   ushort* __restrict__ qs,
                                                   ushort* __restrict__ kk,
                                                   ushort* __restrict__ vt) {
    __shared__ __align__(16) char Al[3][64 * APITCH];    // 3 x 17408 B
    __shared__ __align__(16) char Wl[3][192 * WPITCH];   // 3 x 27648 B

    const int tid = threadIdx.x;
    const int wv  = tid >> 6;         // 0..7
    const int ls  = tid & 63;
    const int r16 = ls & 15;
    const int hi4 = ls >> 4;          // 0..3
    const int g   = wv >> 2;          // rowgroup 0..1
    const int c   = wv & 3;           // colgroup 0..3
    const int row0 = blockIdx.x * 64;

    // ---- staging: linear global sources ----
    const int srow = ls >> 3;         // 0..7
    const int sslt = ls & 7;          // 16B slot 0..7
    const float*  xA  = x + (size_t)(row0 + wv * 8 + srow) * NC + sslt * 4;
    const ushort* wS0 = wt + (size_t)(wv * 24 + 0 + srow) * 1024 + sslt * 8;
    const ushort* wS1 = wt + (size_t)(wv * 24 + 8 + srow) * 1024 + sslt * 8;
    const ushort* wS2 = wt + (size_t)(wv * 24 + 16 + srow) * 1024 + sslt * 8;

    // ---- LDS write byte-offsets (padded linear) ----
    const int aw  = (wv * 8 + srow) * APITCH + sslt * 16;
    const int ww0 = (wv * 24 + 0 + srow) * WPITCH + sslt * 16;
    const int ww1 = (wv * 24 + 8 + srow) * WPITCH + sslt * 16;
    const int ww2 = (wv * 24 + 16 + srow) * WPITCH + sslt * 16;

    // ---- LDS read byte-offsets ----
    int aoff[2];
#pragma unroll
    for (int m = 0; m < 2; ++m)
        aoff[m] = (g * 32 + m * 16 + r16) * APITCH + hi4 * 32;
    int boff[3];
#pragma unroll
    for (int nf = 0; nf < 3; ++nf)
        boff[nf] = (c * 48 + nf * 16 + r16) * WPITCH + hi4 * 16;

    f32x4 acc[2][3];
#pragma unroll
    for (int i = 0; i < 2; ++i)
#pragma unroll
        for (int j = 0; j < 3; ++j)
#pragma unroll
            for (int e = 0; e < 4; ++e) acc[i][j][e] = 0.f;

    struct Stage { float4 xa, xb; uint4 w0, w1, w2; };
    Stage st[3];

    auto LOADS = [&](int t, Stage& s) {
        s.xa = *(const float4*)(xA + t * 64);
        s.xb = *(const float4*)(xA + t * 64 + 32);
        s.w0 = *(const uint4*)(wS0 + t * 64);
        s.w1 = *(const uint4*)(wS1 + t * 64);
        s.w2 = *(const uint4*)(wS2 + t * 64);
    };
    auto WRITE = [&](int t, const Stage& s) {
        int bb = t % 3;
        *(float4*)(&Al[bb][aw])        = s.xa;
        *(float4*)(&Al[bb][aw + 128])  = s.xb;
        *(uint4*)(&Wl[bb][ww0]) = s.w0;
        *(uint4*)(&Wl[bb][ww1]) = s.w1;
        *(uint4*)(&Wl[bb][ww2]) = s.w2;
    };
    auto COMPUTE = [&](int bb) {
#pragma unroll
        for (int kq = 0; kq < 2; ++kq) {
            s16x8 af[2], bf[3];
#pragma unroll
            for (int m = 0; m < 2; ++m) {
                const char* base = &Al[bb][0];
                float4 a0 = *(const float4*)(base + aoff[m] + kq * 128);
                float4 a1 = *(const float4*)(base + aoff[m] + kq * 128 + 16);
                union { uint32_t w[4]; s16x8 v; } pk;
                pk.w[0] = cvt_pk_bf16(a0.x, a0.y);
                pk.w[1] = cvt_pk_bf16(a0.z, a0.w);
                pk.w[2] = cvt_pk_bf16(a1.x, a1.y);
                pk.w[3] = cvt_pk_bf16(a1.z, a1.w);
                af[m] = pk.v;
            }
#pragma unroll
            for (int nf = 0; nf < 3; ++nf)
                bf[nf] = *(const s16x8*)(&Wl[bb][0] + boff[nf] + kq * 64);
#pragma unroll
            for (int m = 0; m < 2; ++m)
#pragma unroll
                for (int nf = 0; nf < 3; ++nf)
                    acc[m][nf] = __builtin_amdgcn_mfma_f32_16x16x32_bf16(
                        af[m], bf[nf], acc[m][nf], 0, 0, 0);
        }
    };

    // ---- prologue: issue loads for steps 0..2, write step 0 ----
    LOADS(0, st[0]); LOADS(1, st[1]); LOADS(2, st[2]);
    WRITE(0, st[0]);
    __builtin_amdgcn_sched_barrier(0);
    asm volatile("s_waitcnt lgkmcnt(0)" ::: "memory");
    __builtin_amdgcn_s_barrier();
    __builtin_amdgcn_sched_barrier(0);

    // ---- main loop: 16 K-steps, fully unrolled ----
#pragma unroll
    for (int t = 0; t < 16; ++t) {
        if (t + 3 <= 15) LOADS(t + 3, st[(t + 3) % 3]);
        if (t + 1 <= 15) WRITE(t + 1, st[(t + 1) % 3]);
        __builtin_amdgcn_sched_barrier(0);
        asm volatile("s_waitcnt lgkmcnt(0)" ::: "memory");
        __builtin_amdgcn_s_barrier();
        __builtin_amdgcn_sched_barrier(0);
        COMPUTE(t % 3);
    }

    // ---- epilogue: scatter to qs / kk / vt(bf16, transposed) ----
    const int b = row0 >> 11;
#pragma unroll
    for (int m = 0; m < 2; ++m) {
        const int rbase = row0 + g * 32 + m * 16 + hi4 * 4;
#pragma unroll
        for (int nf = 0; nf < 3; ++nf) {
            int colg = c * 48 + nf * 16 + r16;   // 0..191
            f32x4 v = acc[m][nf];
            if (colg < 64) {
#pragma unroll
                for (int j = 0; j < 4; ++j)
                    qs[(size_t)(rbase + j) * HD + colg] = f2b(v[j]);
            } else if (colg < 128) {
#pragma unroll
                for (int j = 0; j < 4; ++j)
                    kk[(size_t)(rbase + j) * HD + (colg - 64)] = f2b(v[j]);
            } else {
                int d = colg - 128;
                union { ushort4 s; ushort u[4]; } pk;
#pragma unroll
                for (int j = 0; j < 4; ++j) pk.u[j] = f2b(v[j]);
                *(ushort4*)(&vt[((size_t)(b * 64 + d)) * NT + (rbase & (NT - 1))]) = pk.s;
            }
        }
    }
}

// ---------------------------------------------------------------------------
// Kernel 2: causal flash attention. 4 waves/block, intra-block split-K:
// wave w handles k-tiles w, w+4, ... of its 32-row q-tile; partial
// (m,l,o) merged in LDS with exp2 rescaling. grid = 512, big tiles first.
// ---------------------------------------------------------------------------
__global__ __launch_bounds__(256) void attn(const ushort* __restrict__ qs,
                                            const ushort* __restrict__ kk,
                                            const ushort* __restrict__ vt,
                                            float* __restrict__ out) {
    __shared__ float ob[4][64][33];   // per-wave unnormalized O^T partials
    __shared__ float ml[4][2][32];    // per-wave m / lsum per q col

    const int bid  = blockIdx.x;
    const int b    = bid & 7;
    const int tile = 63 - (bid >> 3);          // big-first for balance
    const int tid  = threadIdx.x;
    const int wv   = tid >> 6;                 // 0..3  (k-split index)
    const int l    = tid & 63;
    const int qcol = l & 31;
    const int hi   = l >> 5;
    const int r0   = tile * 32;

    const ushort* qb = qs + ((size_t)(b * NT + r0)) * HD;
    const ushort* kb = kk + (size_t)b * NT * HD;
    const ushort* vb = vt + (size_t)b * HD * NT;

    s16x8 qf[4];
#pragma unroll
    for (int c = 0; c < 4; ++c)
        qf[c] = *(const s16x8*)(qb + (size_t)qcol * HD + c * 16 + hi * 8);

    f32x16 o0, o1;
#pragma unroll
    for (int i = 0; i < 16; ++i) { o0[i] = 0.f; o1[i] = 0.f; }
    float m = -3.0e30f, lsum = 0.f;

    if (wv <= tile) {
        s16x8 kf[4], vf[4];
        {
            const ushort* kr = kb + (size_t)(wv * 32 + qcol) * HD;
#pragma unroll
            for (int c = 0; c < 4; ++c)
                kf[c] = *(const s16x8*)(kr + c * 16 + hi * 8);
#pragma unroll
            for (int dt = 0; dt < 2; ++dt)
#pragma unroll
                for (int kc = 0; kc < 2; ++kc)
                    vf[dt * 2 + kc] = *(const s16x8*)(vb + (size_t)(dt * 32 + qcol) * NT
                                                      + wv * 32 + kc * 16 + hi * 8);
        }

        for (int kt = wv; kt <= tile; kt += 4) {
            // S^T = K . Q^T   (col = q, row-regs = k_local)
            f32x16 s;
#pragma unroll
            for (int i = 0; i < 16; ++i) s[i] = 0.f;
#pragma unroll
            for (int c = 0; c < 4; ++c)
                s = __builtin_amdgcn_mfma_f32_32x32x16_bf16(kf[c], qf[c], s, 0, 0, 0);

            // prefetch this wave's next K/V tiles (stride 4)
            s16x8 kfn[4], vfn[4];
            const bool more = (kt + 4 <= tile);
            if (more) {
                const ushort* kr = kb + (size_t)((kt + 4) * 32 + qcol) * HD;
#pragma unroll
                for (int c = 0; c < 4; ++c)
                    kfn[c] = *(const s16x8*)(kr + c * 16 + hi * 8);
#pragma unroll
                for (int dt = 0; dt < 2; ++dt)
#pragma unroll
                    for (int kc = 0; kc < 2; ++kc)
                        vfn[dt * 2 + kc] = *(const s16x8*)(vb + (size_t)(dt * 32 + qcol) * NT
                                                           + (kt + 4) * 32 + kc * 16 + hi * 8);
            }

            // online softmax (per-lane scalar state: one q per lane)
            const bool diag = (kt == tile);
            float p[16];
#pragma unroll
            for (int r = 0; r < 16; ++r) {
                int klocal = (r & 3) + 8 * (r >> 2) + 4 * hi;
                float sv = s[r];
                if (diag && klocal > qcol) sv = -3.0e30f;
                p[r] = sv;
            }
            float pmax = p[0];
#pragma unroll
            for (int r = 1; r < 16; ++r) pmax = fmaxf(pmax, p[r]);
            pmax = fmaxf(pmax, __shfl_xor(pmax, 32));
            float mnew = fmaxf(m, pmax);
            float corr = exp2f(m - mnew);
            m = mnew;
            float rs = 0.f;
#pragma unroll
            for (int r = 0; r < 16; ++r) { p[r] = exp2f(p[r] - mnew); rs += p[r]; }
            rs += __shfl_xor(rs, 32);
            lsum = lsum * corr + rs;
#pragma unroll
            for (int i = 0; i < 16; ++i) { o0[i] *= corr; o1[i] *= corr; }

            // P (f32, S^T layout) -> bf16 B-fragments via cvt_pk + lane^32 exchange
#pragma unroll
            for (int kc = 0; kc < 2; ++kc) {
                int pb = kc * 8;
                uint32_t a0 = cvt_pk_bf16(p[pb + 0], p[pb + 1]);
                uint32_t a1 = cvt_pk_bf16(p[pb + 2], p[pb + 3]);
                uint32_t b0 = cvt_pk_bf16(p[pb + 4], p[pb + 5]);
                uint32_t b1 = cvt_pk_bf16(p[pb + 6], p[pb + 7]);
                uint32_t a0x = __shfl_xor(a0, 32);
                uint32_t a1x = __shfl_xor(a1, 32);
                uint32_t b0x = __shfl_xor(b0, 32);
                uint32_t b1x = __shfl_xor(b1, 32);
                union { uint32_t w[4]; s16x8 v; } frag;
                frag.w[0] = hi ? b0x : a0;
                frag.w[1] = hi ? b1x : a1;
                frag.w[2] = hi ? b0  : a0x;
                frag.w[3] = hi ? b1  : a1x;
                o0 = __builtin_amdgcn_mfma_f32_32x32x16_bf16(vf[0 * 2 + kc], frag.v, o0, 0, 0, 0);
                o1 = __builtin_amdgcn_mfma_f32_32x32x16_bf16(vf[1 * 2 + kc], frag.v, o1, 0, 0, 0);
            }

            if (more) {
#pragma unroll
                for (int c = 0; c < 4; ++c) kf[c] = kfn[c];
#pragma unroll
                for (int c = 0; c < 4; ++c) vf[c] = vfn[c];
            }
        }
    }

    // --- write per-wave partials (unnormalized) ---
#pragma unroll
    for (int r = 0; r < 16; ++r) {
        int d = (r & 3) + 8 * (r >> 2) + 4 * hi;
        ob[wv][d][qcol]      = o0[r];
        ob[wv][d + 32][qcol] = o1[r];
    }
    if (hi == 0) {
        ml[wv][0][qcol] = m;
        ml[wv][1][qcol] = lsum;
    }
    __syncthreads();

    // --- merge 4 partials + coalesced f32 store ---
    // thread -> (q = tid>>3, d block of 8 at (tid&7)*8)
    const int q  = tid >> 3;
    const int j0 = (tid & 7) * 8;
    float mw[4];
#pragma unroll
    for (int w = 0; w < 4; ++w) mw[w] = ml[w][0][q];
    float M = fmaxf(fmaxf(mw[0], mw[1]), fmaxf(mw[2], mw[3]));
    float sw[4]; float L = 0.f;
#pragma unroll
    for (int w = 0; w < 4; ++w) {
        sw[w] = exp2f(mw[w] - M);
        L += sw[w] * ml[w][1][q];
    }
    float invL = 1.0f / L;
    float vals[8];
#pragma unroll
    for (int j = 0; j < 8; ++j) {
        int d = j0 + j;
        float acc = 0.f;
#pragma unroll
        for (int w = 0; w < 4; ++w) acc += sw[w] * ob[w][d][q];
        vals[j] = acc * invL;
    }
    float* orow = out + ((size_t)(b * NT + r0 + q)) * HD + j0;
    *(float4*)(orow)     = make_float4(vals[0], vals[1], vals[2], vals[3]);
    *(float4*)(orow + 4) = make_float4(vals[4], vals[5], vals[6], vals[7]);
}

// ---------------------------------------------------------------------------
extern "C" void kernel_launch(void* const* d_in, const int* in_sizes, int n_in,
                              void* d_out, int out_size, void* d_ws, size_t ws_size,
                              hipStream_t stream) {
    const float* x = (const float*)d_in[0];
    const float* W = (const float*)d_in[1];
    float* out = (float*)d_out;

    ushort* qs = (ushort*)d_ws;                 // [8][2048][64] bf16 (pre-scaled q)
    ushort* kk = qs + (size_t)NB * NT * HD;     // [8][2048][64]
    ushort* vt = kk + (size_t)NB * NT * HD;     // [8][64][2048]  (V transposed)
    ushort* wt = vt + (size_t)NB * NT * HD;     // [192][1024]    (W^T bf16)

    wprep<<<768, 256, 0, stream>>>(W, wt);
    qkv_gemm<<<256, 512, 0, stream>>>(x, wt, qs, kk, vt);
    attn<<<512, 256, 0, stream>>>(qs, kk, vt, out);
}

// Round 7
// 57.051 us; speedup vs baseline: 1.7534x; 1.7534x over previous
//
#include <hip/hip_runtime.h>
#include <stdint.h>

#define NB 8
#define NT 2048
#define NC 1024
#define HD 64

typedef __attribute__((ext_vector_type(8)))  short s16x8;
typedef __attribute__((ext_vector_type(4)))  float f32x4;
typedef __attribute__((ext_vector_type(16))) float f32x16;

__device__ inline ushort f2b(float f) {
    union { float f; uint32_t u; } c; c.f = f;
    uint32_t u = c.u;
    uint32_t r = (u + 0x7fffu + ((u >> 16) & 1u)) >> 16;   // RNE, finite inputs
    return (ushort)r;
}

__device__ inline uint32_t cvt_pk_bf16(float lo, float hi) {
    uint32_t r;
    asm("v_cvt_pk_bf16_f32 %0, %1, %2" : "=v"(r) : "v"(lo), "v"(hi));
    return r;
}

__device__ inline void gload_lds16(const void* gsrc, void* lds) {
    __builtin_amdgcn_global_load_lds(
        (const __attribute__((address_space(1))) void*)gsrc,
        (__attribute__((address_space(3))) void*)lds, 16, 0, 0);
}

// ---------------------------------------------------------------------------
// Kernel 0: W [1024][192] f32  ->  Wt [192][1024] bf16, q-cols pre-scaled by
// 0.125 * log2(e) so attention logits are already base-2.
// ---------------------------------------------------------------------------
__global__ __launch_bounds__(256) void wprep(const float* __restrict__ W,
                                             ushort* __restrict__ wt) {
    int tid = blockIdx.x * 256 + threadIdx.x;   // 192*1024 total
    int n = tid >> 10;          // 0..191 (output col of qkv)
    int k = tid & 1023;         // 0..1023
    float v = W[k * 192 + n];
    if (n < 64) v *= 0.125f * 1.4426950408889634f;
    wt[n * 1024 + k] = f2b(v);
}

// ---------------------------------------------------------------------------
// Kernel 1: qkv = x @ W.  BM=64, grid 256 (1 block/CU), 8 waves, BK=64.
// global_load_lds(16B) staging (no VGPR round-trip -> no spill risk).
// Per-CU traffic = x 256 KB + W 384 KB = 640 KB (structural minimum).
// 3 LDS buffers, depth-2 prefetch, counted s_waitcnt vmcnt(5) + s_barrier.
// Both-sides XOR swizzle: global source slot (l&7)^(l>>3); read slot
// S ^ (row&7) -> every quarter-wave spreads over 8 slots = 2-way free.
// A stored f32 (convert on read via cvt_pk); layout A[buf][kq][64][128B],
// W[buf][192][128B]. Wave (g,c): rows g*32..+32, cols c*48..+48.
// ---------------------------------------------------------------------------
__global__ __launch_bounds__(512, 1) void qkv_gemm(const float* __restrict__ x,
                                                   const ushort* __restrict__ wt,
                                                   ushort* __restrict__ qs,
                                                   ushort* __restrict__ kk,
                                                   ushort* __restrict__ vt) {
    __shared__ __align__(16) char Al[3][16384];   // [kq][row][slot*16B]
    __shared__ __align__(16) char Wl[3][24576];   // [row][slot*16B]

    const int tid = threadIdx.x;
    const int wv  = tid >> 6;         // 0..7
    const int ls  = tid & 63;
    const int r16 = ls & 15;
    const int hi4 = ls >> 4;          // 0..3
    const int g   = wv >> 2;          // rowgroup 0..1
    const int c   = wv & 3;           // colgroup 0..3
    const int row0 = blockIdx.x * 64;

    // ---- staging sources (pre-swizzled 16B slot within each 128B row-half) ----
    const int srow = ls >> 3;               // 0..7
    const int sslt = (ls & 7) ^ srow;       // swizzled slot
    const float* xA = x + (size_t)(row0 + wv * 8 + srow) * NC + sslt * 4;
    const ushort* wS0 = wt + (size_t)(wv * 24 + 0  + srow) * 1024 + sslt * 8;
    const ushort* wS1 = wt + (size_t)(wv * 24 + 8  + srow) * 1024 + sslt * 8;
    const ushort* wS2 = wt + (size_t)(wv * 24 + 16 + srow) * 1024 + sslt * 8;

    // ---- read offsets ----
    const int key = r16 & 7;
    int aoff[2];                       // + kq*8192 at read; a1 = a0 ^ 16
#pragma unroll
    for (int m = 0; m < 2; ++m)
        aoff[m] = (g * 32 + m * 16 + r16) * 128 + (((hi4 * 2) ^ key) << 4);
    int bnrow[3];
#pragma unroll
    for (int nf = 0; nf < 3; ++nf)
        bnrow[nf] = (c * 48 + nf * 16 + r16) * 128;
    int bkey[2];
#pragma unroll
    for (int kq = 0; kq < 2; ++kq)
        bkey[kq] = ((kq * 4 + hi4) ^ key) << 4;

    f32x4 acc[2][3];
#pragma unroll
    for (int i = 0; i < 2; ++i)
#pragma unroll
        for (int j = 0; j < 3; ++j)
#pragma unroll
            for (int e = 0; e < 4; ++e) acc[i][j][e] = 0.f;

    auto STAGE = [&](int t) {
        int bb = t % 3;
        gload_lds16(xA + t * 64,      &Al[bb][0 * 8192 + wv * 1024]);
        gload_lds16(xA + t * 64 + 32, &Al[bb][1 * 8192 + wv * 1024]);
        gload_lds16(wS0 + t * 64, &Wl[bb][(wv * 24 + 0) * 128]);
        gload_lds16(wS1 + t * 64, &Wl[bb][(wv * 24 + 8) * 128]);
        gload_lds16(wS2 + t * 64, &Wl[bb][(wv * 24 + 16) * 128]);
    };

    auto COMPUTE = [&](int bb) {
#pragma unroll
        for (int kq = 0; kq < 2; ++kq) {
            s16x8 af[2], bf[3];
#pragma unroll
            for (int m = 0; m < 2; ++m) {
                const char* base = &Al[bb][kq * 8192];
                float4 a0 = *(const float4*)(base + aoff[m]);
                float4 a1 = *(const float4*)(base + (aoff[m] ^ 16));
                union { uint32_t w[4]; s16x8 v; } pk;
                pk.w[0] = cvt_pk_bf16(a0.x, a0.y);
                pk.w[1] = cvt_pk_bf16(a0.z, a0.w);
                pk.w[2] = cvt_pk_bf16(a1.x, a1.y);
                pk.w[3] = cvt_pk_bf16(a1.z, a1.w);
                af[m] = pk.v;
            }
#pragma unroll
            for (int nf = 0; nf < 3; ++nf)
                bf[nf] = *(const s16x8*)(&Wl[bb][0] + bnrow[nf] + bkey[kq]);
#pragma unroll
            for (int m = 0; m < 2; ++m)
#pragma unroll
                for (int nf = 0; nf < 3; ++nf)
                    acc[m][nf] = __builtin_amdgcn_mfma_f32_16x16x32_bf16(
                        af[m], bf[nf], acc[m][nf], 0, 0, 0);
        }
    };

    // ---- prologue: stage steps 0,1 (10 vm-ops outstanding/wave) ----
    STAGE(0); STAGE(1);

    // ---- main loop: 16 K-steps ----
    for (int t = 0; t < 14; ++t) {
        asm volatile("s_waitcnt vmcnt(5)" ::: "memory");   // stage t landed
        __builtin_amdgcn_s_barrier();
        STAGE(t + 2);
        COMPUTE(t % 3);
    }
    asm volatile("s_waitcnt vmcnt(5)" ::: "memory");
    __builtin_amdgcn_s_barrier();
    COMPUTE(14 % 3);
    asm volatile("s_waitcnt vmcnt(0)" ::: "memory");
    __builtin_amdgcn_s_barrier();
    COMPUTE(15 % 3);

    // ---- epilogue: scatter to qs / kk / vt(bf16, transposed) ----
    const int b = row0 >> 11;
#pragma unroll
    for (int m = 0; m < 2; ++m) {
        const int rbase = row0 + g * 32 + m * 16 + hi4 * 4;
#pragma unroll
        for (int nf = 0; nf < 3; ++nf) {
            int colg = c * 48 + nf * 16 + r16;   // 0..191
            f32x4 v = acc[m][nf];
            if (colg < 64) {
#pragma unroll
                for (int j = 0; j < 4; ++j)
                    qs[(size_t)(rbase + j) * HD + colg] = f2b(v[j]);
            } else if (colg < 128) {
#pragma unroll
                for (int j = 0; j < 4; ++j)
                    kk[(size_t)(rbase + j) * HD + (colg - 64)] = f2b(v[j]);
            } else {
                int d = colg - 128;
                union { ushort4 s; ushort u[4]; } pk;
#pragma unroll
                for (int j = 0; j < 4; ++j) pk.u[j] = f2b(v[j]);
                *(ushort4*)(&vt[((size_t)(b * 64 + d)) * NT + (rbase & (NT - 1))]) = pk.s;
            }
        }
    }
}

// ---------------------------------------------------------------------------
// Kernel 2: causal flash attention. 4 waves/block, intra-block split-K:
// wave w handles k-tiles w, w+4, ... of its 32-row q-tile; partial
// (m,l,o) merged in LDS with exp2 rescaling. grid = 512, big tiles first.
// ---------------------------------------------------------------------------
__global__ __launch_bounds__(256) void attn(const ushort* __restrict__ qs,
                                            const ushort* __restrict__ kk,
                                            const ushort* __restrict__ vt,
                                            float* __restrict__ out) {
    __shared__ float ob[4][64][33];   // per-wave unnormalized O^T partials
    __shared__ float ml[4][2][32];    // per-wave m / lsum per q col

    const int bid  = blockIdx.x;
    const int b    = bid & 7;
    const int tile = 63 - (bid >> 3);          // big-first for balance
    const int tid  = threadIdx.x;
    const int wv   = tid >> 6;                 // 0..3  (k-split index)
    const int l    = tid & 63;
    const int qcol = l & 31;
    const int hi   = l >> 5;
    const int r0   = tile * 32;

    const ushort* qb = qs + ((size_t)(b * NT + r0)) * HD;
    const ushort* kb = kk + (size_t)b * NT * HD;
    const ushort* vb = vt + (size_t)b * HD * NT;

    s16x8 qf[4];
#pragma unroll
    for (int c = 0; c < 4; ++c)
        qf[c] = *(const s16x8*)(qb + (size_t)qcol * HD + c * 16 + hi * 8);

    f32x16 o0, o1;
#pragma unroll
    for (int i = 0; i < 16; ++i) { o0[i] = 0.f; o1[i] = 0.f; }
    float m = -3.0e30f, lsum = 0.f;

    if (wv <= tile) {
        s16x8 kf[4], vf[4];
        {
            const ushort* kr = kb + (size_t)(wv * 32 + qcol) * HD;
#pragma unroll
            for (int c = 0; c < 4; ++c)
                kf[c] = *(const s16x8*)(kr + c * 16 + hi * 8);
#pragma unroll
            for (int dt = 0; dt < 2; ++dt)
#pragma unroll
                for (int kc = 0; kc < 2; ++kc)
                    vf[dt * 2 + kc] = *(const s16x8*)(vb + (size_t)(dt * 32 + qcol) * NT
                                                      + wv * 32 + kc * 16 + hi * 8);
        }

        for (int kt = wv; kt <= tile; kt += 4) {
            // S^T = K . Q^T   (col = q, row-regs = k_local)
            f32x16 s;
#pragma unroll
            for (int i = 0; i < 16; ++i) s[i] = 0.f;
#pragma unroll
            for (int c = 0; c < 4; ++c)
                s = __builtin_amdgcn_mfma_f32_32x32x16_bf16(kf[c], qf[c], s, 0, 0, 0);

            // prefetch this wave's next K/V tiles (stride 4)
            s16x8 kfn[4], vfn[4];
            const bool more = (kt + 4 <= tile);
            if (more) {
                const ushort* kr = kb + (size_t)((kt + 4) * 32 + qcol) * HD;
#pragma unroll
                for (int c = 0; c < 4; ++c)
                    kfn[c] = *(const s16x8*)(kr + c * 16 + hi * 8);
#pragma unroll
                for (int dt = 0; dt < 2; ++dt)
#pragma unroll
                    for (int kc = 0; kc < 2; ++kc)
                        vfn[dt * 2 + kc] = *(const s16x8*)(vb + (size_t)(dt * 32 + qcol) * NT
                                                           + (kt + 4) * 32 + kc * 16 + hi * 8);
            }

            // online softmax (per-lane scalar state: one q per lane)
            const bool diag = (kt == tile);
            float p[16];
#pragma unroll
            for (int r = 0; r < 16; ++r) {
                int klocal = (r & 3) + 8 * (r >> 2) + 4 * hi;
                float sv = s[r];
                if (diag && klocal > qcol) sv = -3.0e30f;
                p[r] = sv;
            }
            float pmax = p[0];
#pragma unroll
            for (int r = 1; r < 16; ++r) pmax = fmaxf(pmax, p[r]);
            pmax = fmaxf(pmax, __shfl_xor(pmax, 32));
            float mnew = fmaxf(m, pmax);
            float corr = exp2f(m - mnew);
            m = mnew;
            float rs = 0.f;
#pragma unroll
            for (int r = 0; r < 16; ++r) { p[r] = exp2f(p[r] - mnew); rs += p[r]; }
            rs += __shfl_xor(rs, 32);
            lsum = lsum * corr + rs;
#pragma unroll
            for (int i = 0; i < 16; ++i) { o0[i] *= corr; o1[i] *= corr; }

            // P (f32, S^T layout) -> bf16 B-fragments via cvt_pk + lane^32 exchange
#pragma unroll
            for (int kc = 0; kc < 2; ++kc) {
                int pb = kc * 8;
                uint32_t a0 = cvt_pk_bf16(p[pb + 0], p[pb + 1]);
                uint32_t a1 = cvt_pk_bf16(p[pb + 2], p[pb + 3]);
                uint32_t b0 = cvt_pk_bf16(p[pb + 4], p[pb + 5]);
                uint32_t b1 = cvt_pk_bf16(p[pb + 6], p[pb + 7]);
                uint32_t a0x = __shfl_xor(a0, 32);
                uint32_t a1x = __shfl_xor(a1, 32);
                uint32_t b0x = __shfl_xor(b0, 32);
                uint32_t b1x = __shfl_xor(b1, 32);
                union { uint32_t w[4]; s16x8 v; } frag;
                frag.w[0] = hi ? b0x : a0;
                frag.w[1] = hi ? b1x : a1;
                frag.w[2] = hi ? b0  : a0x;
                frag.w[3] = hi ? b1  : a1x;
                o0 = __builtin_amdgcn_mfma_f32_32x32x16_bf16(vf[0 * 2 + kc], frag.v, o0, 0, 0, 0);
                o1 = __builtin_amdgcn_mfma_f32_32x32x16_bf16(vf[1 * 2 + kc], frag.v, o1, 0, 0, 0);
            }

            if (more) {
#pragma unroll
                for (int c = 0; c < 4; ++c) kf[c] = kfn[c];
#pragma unroll
                for (int c = 0; c < 4; ++c) vf[c] = vfn[c];
            }
        }
    }

    // --- write per-wave partials (unnormalized) ---
#pragma unroll
    for (int r = 0; r < 16; ++r) {
        int d = (r & 3) + 8 * (r >> 2) + 4 * hi;
        ob[wv][d][qcol]      = o0[r];
        ob[wv][d + 32][qcol] = o1[r];
    }
    if (hi == 0) {
        ml[wv][0][qcol] = m;
        ml[wv][1][qcol] = lsum;
    }
    __syncthreads();

    // --- merge 4 partials + coalesced f32 store ---
    // thread -> (q = tid>>3, d block of 8 at (tid&7)*8)
    const int q  = tid >> 3;
    const int j0 = (tid & 7) * 8;
    float mw[4];
#pragma unroll
    for (int w = 0; w < 4; ++w) mw[w] = ml[w][0][q];
    float M = fmaxf(fmaxf(mw[0], mw[1]), fmaxf(mw[2], mw[3]));
    float sw[4]; float L = 0.f;
#pragma unroll
    for (int w = 0; w < 4; ++w) {
        sw[w] = exp2f(mw[w] - M);
        L += sw[w] * ml[w][1][q];
    }
    float invL = 1.0f / L;
    float vals[8];
#pragma unroll
    for (int j = 0; j < 8; ++j) {
        int d = j0 + j;
        float acc = 0.f;
#pragma unroll
        for (int w = 0; w < 4; ++w) acc += sw[w] * ob[w][d][q];
        vals[j] = acc * invL;
    }
    float* orow = out + ((size_t)(b * NT + r0 + q)) * HD + j0;
    *(float4*)(orow)     = make_float4(vals[0], vals[1], vals[2], vals[3]);
    *(float4*)(orow + 4) = make_float4(vals[4], vals[5], vals[6], vals[7]);
}

// ---------------------------------------------------------------------------
extern "C" void kernel_launch(void* const* d_in, const int* in_sizes, int n_in,
                              void* d_out, int out_size, void* d_ws, size_t ws_size,
                              hipStream_t stream) {
    const float* x = (const float*)d_in[0];
    const float* W = (const float*)d_in[1];
    float* out = (float*)d_out;

    ushort* qs = (ushort*)d_ws;                 // [8][2048][64] bf16 (pre-scaled q)
    ushort* kk = qs + (size_t)NB * NT * HD;     // [8][2048][64]
    ushort* vt = kk + (size_t)NB * NT * HD;     // [8][64][2048]  (V transposed)
    ushort* wt = vt + (size_t)NB * NT * HD;     // [192][1024]    (W^T bf16)

    wprep<<<768, 256, 0, stream>>>(W, wt);
    qkv_gemm<<<256, 512, 0, stream>>>(x, wt, qs, kk, vt);
    attn<<<512, 256, 0, stream>>>(qs, kk, vt, out);
}